// Round 6
// baseline (450.493 us; speedup 1.0000x reference)
//
#include <hip/hip_runtime.h>
#include <hip/hip_bf16.h>

// GCN: h = (0.5A)^2 x ; h = relu(h W1 + b1) ; h = (0.5A)^2 h ; h = h W2 + b2
// r18: fuse the 5-kernel CSR build into ONE kernel with a device-scope
//  generation grid-barrier (256 blocks <= 256 CUs -> co-residency guaranteed,
//  no occupancy arithmetic needed). Tests the ~70us "unaccounted" budget
//  hypothesis: ~8 dispatch boundaries x ~5-8us launch/drain overhead.
//  Phases: P1 convert+wfrag+hist | P2 region scan (blk0) | P3 base scan |
//          P4 coarse scatter | P5 region sort.  4 barriers.
//  Cross-XCD visibility: all inter-phase data crosses the barrier's
//  device-scope acq/rel (__hip_atomic_* AGENT scope + __threadfence).
//  spmm kernels byte-identical to r17 (284.2us) for clean attribution.
// Dispatches: memset(16B) + build_fused + S1 + S2f + S3 + S4 = 6 (was 9).
// Buffers (d_out used as raw scratch until final write):
//  xb  = d_out[0,6.4MB)   t0b = d_out[6.4,12.8MB)   t2b = d_out[12.8,25.6MB)
//  ws: t3b[0,12.8MB) (stg int2 overlays, dead by P5 end) | row_ptr N+1 |
//      region_off NREG+1 | partial 256*256 | W1f 4KB | W2f 8KB | cv E*4B | bar

#define REGION_SHIFT 9               // 512 rows per region
#define REGION_SIZE  (1 << REGION_SHIFT)
#define COL_MASK 0x1FFFF             // 17 bits, N=100000 < 131072
#define NBLK 256                     // build grid; <= #CUs -> all co-resident

typedef unsigned short u16;
typedef unsigned int   u32;
typedef __attribute__((ext_vector_type(8))) short bf16x8;
typedef __attribute__((ext_vector_type(4))) float f32x4;

__device__ inline float bflo(u32 w) { return __uint_as_float(w << 16); }
__device__ inline float bfhi(u32 w) { return __uint_as_float(w & 0xffff0000u); }
// pack two fp32 -> bf16 pair (RTN-even), a in low half
__device__ inline u32 bfpack(float a, float b) {
    u32 ua = __float_as_uint(a), ub = __float_as_uint(b);
    ua = (ua + 0x7fffu + ((ua >> 16) & 1u)) >> 16;
    ub = (ub + 0x7fffu + ((ub >> 16) & 1u)) & 0xffff0000u;
    return ua | ub;
}
__device__ inline u16 bf1(float f) {
    u32 u = __float_as_uint(f);
    return (u16)((u + 0x7fffu + ((u >> 16) & 1u)) >> 16);
}

// Device-scope generation barrier. All NBLK blocks are co-resident
// (NBLK <= CU count), so spinning is safe. bar[0]=count, bar[1]=generation.
__device__ inline void gridbar(int* __restrict__ bar) {
    __syncthreads();
    if (threadIdx.x == 0) {
        __threadfence();   // make this block's prior global writes visible
        int g = __hip_atomic_load(&bar[1], __ATOMIC_RELAXED, __HIP_MEMORY_SCOPE_AGENT);
        int a = __hip_atomic_fetch_add(&bar[0], 1, __ATOMIC_ACQ_REL, __HIP_MEMORY_SCOPE_AGENT);
        if (a == NBLK - 1) {
            __hip_atomic_store(&bar[0], 0, __ATOMIC_RELAXED, __HIP_MEMORY_SCOPE_AGENT);
            __hip_atomic_fetch_add(&bar[1], 1, __ATOMIC_ACQ_REL, __HIP_MEMORY_SCOPE_AGENT);
        } else {
            while (__hip_atomic_load(&bar[1], __ATOMIC_ACQUIRE, __HIP_MEMORY_SCOPE_AGENT) == g)
                __builtin_amdgcn_s_sleep(8);
        }
        __threadfence();   // acquire side: invalidate stale cached lines
    }
    __syncthreads();
}

// ---- fused CSR build: convert + wfrag + hist | scan | base | scatter | sort
__global__ __launch_bounds__(256) void build_fused_kernel(
        const int* __restrict__ er, const int* __restrict__ ec,
        const float* __restrict__ ev, int E,
        const float* __restrict__ x, u16* __restrict__ xb, int n4,
        const float* __restrict__ W1, const float* __restrict__ W2,
        u16* __restrict__ W1f, u16* __restrict__ W2f,
        int* __restrict__ partial, int* __restrict__ region_off,
        int2* __restrict__ stg, int* __restrict__ row_ptr,
        u32* __restrict__ cv, int N, int nreg, int* __restrict__ bar) {
    __shared__ int sh_a[REGION_SIZE];   // P1: hist256 | P4: cnt2 | P5: hist512
    __shared__ int sh_b[REGION_SIZE];   // P4: gbase   | P5: wp512
    __shared__ int sh_p[256];           // scans
    int t  = threadIdx.x;
    int cb = blockIdx.x;

    // ---------- P1: fp32->bf16 convert + weight frags + region hist --------
    for (int i = cb * 256 + t; i < n4; i += NBLK * 256) {
        float4 a = reinterpret_cast<const float4*>(x)[i];
        uint2 o;
        o.x = bfpack(a.x, a.y);
        o.y = bfpack(a.z, a.w);
        reinterpret_cast<uint2*>(xb)[i] = o;
    }
    if (cb == 0) {
        // W1f[t][quad][n16][j] = bf16(W1[(quad*8+j)*64 + t*16 + n16])
        for (int idx = t; idx < 2048; idx += 256) {
            int j = idx & 7, n16 = (idx >> 3) & 15;
            int quad = (idx >> 7) & 3, tt = (idx >> 9) & 3;
            W1f[idx] = bf1(W1[(quad * 8 + j) * 64 + tt * 16 + n16]);
        }
        // W2f[t][half][quad][n16][j] = bf16(W2[(half*32+quad*8+j)*64 + t*16 + n16])
        for (int idx = t; idx < 4096; idx += 256) {
            int j = idx & 7, n16 = (idx >> 3) & 15;
            int quad = (idx >> 7) & 3, half = (idx >> 9) & 1, tt = (idx >> 10) & 3;
            W2f[idx] = bf1(W2[(half * 32 + quad * 8 + j) * 64 + tt * 16 + n16]);
        }
    }
    sh_a[t] = 0;
    __syncthreads();
    int chunk = (E + NBLK - 1) / NBLK;
    int s0 = cb * chunk;
    int e0 = min(E, s0 + chunk);
    for (int i = s0 + t; i < e0; i += 256)
        atomicAdd(&sh_a[er[i] >> REGION_SHIFT], 1);
    __syncthreads();
    partial[cb * 256 + t] = sh_a[t];     // single-writer 1KB row
    gridbar(bar);

    // ---------- P2: block 0: region totals -> exclusive scan -> region_off -
    if (cb == 0) {
        int total = 0;
        if (t < nreg)
            for (int b = 0; b < NBLK; b++) total += partial[b * 256 + t];  // coalesced
        sh_p[t] = (t < nreg) ? total : 0;
        __syncthreads();
        for (int off = 1; off < 256; off <<= 1) {
            int xv = (t >= off) ? sh_p[t - off] : 0;
            __syncthreads();
            sh_p[t] += xv;
            __syncthreads();
        }
        if (t < nreg) region_off[t] = sh_p[t] - total;
        if (t == 0) region_off[nreg] = E;
    }
    gridbar(bar);

    // ---------- P3: per-region scan over blocks: partial -> scatter bases --
    if (cb < nreg) {
        int c = partial[t * 256 + cb];   // block t's count for region cb
        sh_p[t] = c;
        __syncthreads();
        for (int off = 1; off < 256; off <<= 1) {
            int xv = (t >= off) ? sh_p[t - off] : 0;
            __syncthreads();
            sh_p[t] += xv;
            __syncthreads();
        }
        partial[t * 256 + cb] = region_off[cb] + sh_p[t] - c;  // exclusive base
    }
    gridbar(bar);

    // ---------- P4: coarse scatter, LDS rank only (same chunking as P1) ----
    sh_a[t] = 0;                         // cnt2
    sh_b[t] = partial[cb * 256 + t];     // gbase
    __syncthreads();
    for (int i = s0 + t; i < e0; i += 256) {
        int r = er[i];
        int b = r >> REGION_SHIFT;
        int rank = atomicAdd(&sh_a[b], 1);
        int2 rec;
        rec.x = ec[i] | ((r & (REGION_SIZE - 1)) << 17);
        rec.y = (int)bf1(0.5f * ev[i]);  // positive: 15 bits
        stg[sh_b[b] + rank] = rec;       // block-private run
    }
    gridbar(bar);

    // ---------- P5: per-region LDS sort -> row_ptr + packed 4B cv ----------
    if (cb < nreg) {
        int lo = cb << REGION_SHIFT;
        int hi = min(lo + REGION_SIZE, N);
        int cnt = hi - lo;
        for (int r = t; r < cnt; r += 256) sh_a[r] = 0;   // hist512
        __syncthreads();
        int start = region_off[cb];
        int end   = region_off[cb + 1];
        for (int q = start + t; q < end; q += 256)
            atomicAdd(&sh_a[stg[q].x >> 17], 1);
        __syncthreads();
        int a0 = (2 * t     < cnt) ? sh_a[2 * t]     : 0;
        int a1 = (2 * t + 1 < cnt) ? sh_a[2 * t + 1] : 0;
        sh_p[t] = a0 + a1;
        __syncthreads();
        for (int off = 1; off < 256; off <<= 1) {
            int xv = (t >= off) ? sh_p[t - off] : 0;
            __syncthreads();
            sh_p[t] += xv;
            __syncthreads();
        }
        int excl = sh_p[t] - (a0 + a1);
        if (2 * t < cnt) {
            sh_b[2 * t] = start + excl;
            row_ptr[lo + 2 * t] = start + excl;
        }
        if (2 * t + 1 < cnt) {
            sh_b[2 * t + 1] = start + excl + a0;
            row_ptr[lo + 2 * t + 1] = start + excl + a0;
        }
        if (cb == 0 && t == 0) row_ptr[N] = E;
        __syncthreads();
        for (int q = start + t; q < end; q += 256) {
            int2 e = stg[q];
            int lr = e.x >> 17;
            int p = atomicAdd(&sh_b[lr], 1);  // LDS atomic
            cv[p] = ((u32)e.y << 17) | ((u32)e.x & COL_MASK);  // private window
        }
    }
}

// ---------------- CSR SpMM, gather-side, bf16 table / fp32 accum ------------
__device__ inline void fma8(float acc[8], float v, uint4 w) {
    acc[0] = fmaf(v, bflo(w.x), acc[0]); acc[1] = fmaf(v, bfhi(w.x), acc[1]);
    acc[2] = fmaf(v, bflo(w.y), acc[2]); acc[3] = fmaf(v, bfhi(w.y), acc[3]);
    acc[4] = fmaf(v, bflo(w.z), acc[4]); acc[5] = fmaf(v, bfhi(w.z), acc[5]);
    acc[6] = fmaf(v, bflo(w.w), acc[6]); acc[7] = fmaf(v, bfhi(w.w), acc[7]);
}
__device__ inline float cvval(u32 q) { return __uint_as_float((q >> 17) << 16); }

// Shared spmm inner loop: 8 gathers in flight (MLP), then 4-wide, scalar tail.
template <int D>
__device__ inline void spmm_row(const u16* __restrict__ h,
                                const u32* __restrict__ cv,
                                int start, int end, int sub, float acc[8]) {
    int j = start;
    for (; j + 8 <= end; j += 8) {
        u32 q0 = cv[j],     q1 = cv[j + 1], q2 = cv[j + 2], q3 = cv[j + 3];
        u32 q4 = cv[j + 4], q5 = cv[j + 5], q6 = cv[j + 6], q7 = cv[j + 7];
        uint4 w0 = reinterpret_cast<const uint4*>(h + (size_t)(q0 & COL_MASK) * D)[sub];
        uint4 w1 = reinterpret_cast<const uint4*>(h + (size_t)(q1 & COL_MASK) * D)[sub];
        uint4 w2 = reinterpret_cast<const uint4*>(h + (size_t)(q2 & COL_MASK) * D)[sub];
        uint4 w3 = reinterpret_cast<const uint4*>(h + (size_t)(q3 & COL_MASK) * D)[sub];
        uint4 w4 = reinterpret_cast<const uint4*>(h + (size_t)(q4 & COL_MASK) * D)[sub];
        uint4 w5 = reinterpret_cast<const uint4*>(h + (size_t)(q5 & COL_MASK) * D)[sub];
        uint4 w6 = reinterpret_cast<const uint4*>(h + (size_t)(q6 & COL_MASK) * D)[sub];
        uint4 w7 = reinterpret_cast<const uint4*>(h + (size_t)(q7 & COL_MASK) * D)[sub];
        fma8(acc, cvval(q0), w0);
        fma8(acc, cvval(q1), w1);
        fma8(acc, cvval(q2), w2);
        fma8(acc, cvval(q3), w3);
        fma8(acc, cvval(q4), w4);
        fma8(acc, cvval(q5), w5);
        fma8(acc, cvval(q6), w6);
        fma8(acc, cvval(q7), w7);
    }
    for (; j + 4 <= end; j += 4) {
        u32 q0 = cv[j], q1 = cv[j + 1], q2 = cv[j + 2], q3 = cv[j + 3];
        uint4 w0 = reinterpret_cast<const uint4*>(h + (size_t)(q0 & COL_MASK) * D)[sub];
        uint4 w1 = reinterpret_cast<const uint4*>(h + (size_t)(q1 & COL_MASK) * D)[sub];
        uint4 w2 = reinterpret_cast<const uint4*>(h + (size_t)(q2 & COL_MASK) * D)[sub];
        uint4 w3 = reinterpret_cast<const uint4*>(h + (size_t)(q3 & COL_MASK) * D)[sub];
        fma8(acc, cvval(q0), w0);
        fma8(acc, cvval(q1), w1);
        fma8(acc, cvval(q2), w2);
        fma8(acc, cvval(q3), w3);
    }
    for (; j < end; j++) {
        u32 q = cv[j];
        uint4 w = reinterpret_cast<const uint4*>(h + (size_t)(q & COL_MASK) * D)[sub];
        fma8(acc, cvval(q), w);
    }
}

// D features/row; 8 features (16B) per lane; LPR = D/8 lanes per row.
template <int D, bool FINAL>
__global__ __launch_bounds__(256) void spmm_bf16_kernel(
        const u16* __restrict__ h,
        const int* __restrict__ row_ptr,
        const u32* __restrict__ cv,
        void* __restrict__ outp,
        const float* __restrict__ bias,  // used iff FINAL
        int N) {
    constexpr int LPR = D / 8;
    int gid = blockIdx.x * 256 + threadIdx.x;
    int row = gid / LPR;
    int sub = gid % LPR;
    if (row >= N) return;
    int start = row_ptr[row];
    int end   = row_ptr[row + 1];
    float acc[8] = {0.f, 0.f, 0.f, 0.f, 0.f, 0.f, 0.f, 0.f};
    spmm_row<D>(h, cv, start, end, sub, acc);
    if (FINAL) {
        float* op = (float*)outp + (size_t)row * 64 + sub * 8;
#pragma unroll
        for (int k = 0; k < 8; k++) acc[k] += bias[sub * 8 + k];
        reinterpret_cast<float4*>(op)[0] = make_float4(acc[0], acc[1], acc[2], acc[3]);
        reinterpret_cast<float4*>(op)[1] = make_float4(acc[4], acc[5], acc[6], acc[7]);
    } else {
        u16* ob = (u16*)outp + (size_t)row * D + sub * 8;
        uint4 o;
        o.x = bfpack(acc[0], acc[1]);
        o.y = bfpack(acc[2], acc[3]);
        o.z = bfpack(acc[4], acc[5]);
        o.w = bfpack(acc[6], acc[7]);
        reinterpret_cast<uint4*>(ob)[0] = o;
    }
}

// ---- S2f: spmm32 + dense fused: t2 = relu(spmm(t0)@W1 + b1) @ W2 ----------
// Block = 256 thr = 4 waves; LPR=4 -> 64 rows/block = one 16-row tile/wave.
// spmm acc -> LDS tile (bf16) -> per-wave 16x16x32 MFMA (verified r10 layout).
__global__ __launch_bounds__(256) void spmm_dense_kernel(
        const u16* __restrict__ h,       // t0b [N,32] bf16
        const int* __restrict__ row_ptr,
        const u32* __restrict__ cv,
        const u16* __restrict__ W1f,     // [4][4][16][8] bf16 frags
        const float* __restrict__ b1,    // [64]
        const u16* __restrict__ W2f,     // [4][2][4][16][8] bf16 frags
        u16* __restrict__ outb,          // t2b [N,64] bf16
        int N) {
    __shared__ __align__(16) u16 tiles[4][16][80];   // pad 80 (160B = 16B-mult)
    int tid = threadIdx.x;
    int lane = tid & 63;
    int wave = tid >> 6;
    int tilebase = blockIdx.x * 64 + wave * 16;
    if (tilebase >= N) return;           // wave-uniform (N % 16 == 0)
    int gid = blockIdx.x * 256 + tid;
    int row = gid >> 2;                  // LPR = 4
    int sub = gid & 3;

    // ---- spmm D=32 ----
    bool vr = row < N;
    int start = vr ? row_ptr[row] : 0;
    int end   = vr ? row_ptr[row + 1] : 0;
    float acc[8] = {0.f, 0.f, 0.f, 0.f, 0.f, 0.f, 0.f, 0.f};
    spmm_row<32>(h, cv, start, end, sub, acc);

    // ---- stash t1 tile in LDS as bf16 (per-wave private; in-order DS) ----
    u16 (*tile)[80] = tiles[wave];
    {
        uint4 o;
        o.x = bfpack(acc[0], acc[1]);
        o.y = bfpack(acc[2], acc[3]);
        o.z = bfpack(acc[4], acc[5]);
        o.w = bfpack(acc[6], acc[7]);
        *reinterpret_cast<uint4*>(&tile[lane >> 2][sub * 8]) = o;
    }

    // ---- dense: relu(t1@W1+b1)@W2 on MFMA 16x16x32 (verified r10 layout) --
    int n16 = lane & 15;
    int quad = lane >> 4;
    bf16x8 w1f[4];
    bf16x8 w2f[4][2];
#pragma unroll
    for (int t = 0; t < 4; t++) {
        w1f[t] = *reinterpret_cast<const bf16x8*>(&W1f[((t * 4 + quad) * 16 + n16) * 8]);
        w2f[t][0] = *reinterpret_cast<const bf16x8*>(&W2f[(((t * 2 + 0) * 4 + quad) * 16 + n16) * 8]);
        w2f[t][1] = *reinterpret_cast<const bf16x8*>(&W2f[(((t * 2 + 1) * 4 + quad) * 16 + n16) * 8]);
    }
    float b1v[4];
#pragma unroll
    for (int t = 0; t < 4; t++) b1v[t] = b1[t * 16 + n16];

    bf16x8 a1 = *reinterpret_cast<const bf16x8*>(&tile[n16][quad * 8]);
    f32x4 zero = {0.f, 0.f, 0.f, 0.f};
    f32x4 c[4];
#pragma unroll
    for (int t = 0; t < 4; t++)
        c[t] = __builtin_amdgcn_mfma_f32_16x16x32_bf16(a1, w1f[t], zero, 0, 0, 0);

#pragma unroll
    for (int t = 0; t < 4; t++)
#pragma unroll
        for (int i = 0; i < 4; i++)
            tile[quad * 4 + i][t * 16 + n16] = bf1(fmaxf(c[t][i] + b1v[t], 0.f));

    bf16x8 a2_0 = *reinterpret_cast<const bf16x8*>(&tile[n16][quad * 8]);
    bf16x8 a2_1 = *reinterpret_cast<const bf16x8*>(&tile[n16][32 + quad * 8]);
    f32x4 d[4];
#pragma unroll
    for (int t = 0; t < 4; t++) {
        d[t] = __builtin_amdgcn_mfma_f32_16x16x32_bf16(a2_0, w2f[t][0], zero, 0, 0, 0);
        d[t] = __builtin_amdgcn_mfma_f32_16x16x32_bf16(a2_1, w2f[t][1], d[t], 0, 0, 0);
    }

#pragma unroll
    for (int t = 0; t < 4; t++)
#pragma unroll
        for (int i = 0; i < 4; i++)
            tile[quad * 4 + i][t * 16 + n16] = bf1(d[t][i]);

#pragma unroll
    for (int half = 0; half < 2; half++) {
        int g = half * 512 + lane * 8;
        int r = g >> 6, cc = g & 63;
        int grow = tilebase + r;
        if (grow < N)
            *reinterpret_cast<uint4*>(outb + (size_t)grow * 64 + cc) =
                *reinterpret_cast<const uint4*>(&tile[r][cc]);
    }
}

extern "C" void kernel_launch(void* const* d_in, const int* in_sizes, int n_in,
                              void* d_out, int out_size, void* d_ws, size_t ws_size,
                              hipStream_t stream) {
    const float* x        = (const float*)d_in[0];
    const float* edge_val = (const float*)d_in[1];
    const int*   edge_row = (const int*)d_in[2];
    const int*   edge_col = (const int*)d_in[3];
    const float* W1       = (const float*)d_in[4];
    const float* b1       = (const float*)d_in[5];
    const float* W2       = (const float*)d_in[6];
    const float* b2       = (const float*)d_in[7];
    float* out = (float*)d_out;

    const int N = in_sizes[0] / 32;   // 100000
    const int E = in_sizes[1];        // 1600000
    const int NREG = (N + REGION_SIZE - 1) >> REGION_SHIFT;  // 196

    // --- d_out as raw scratch (fp32 final write overwrites all) ---
    u16* xb  = (u16*)d_out;                    // N*32 bf16
    u16* t0b = xb + (size_t)N * 32;            // N*32 bf16
    u16* t2b = (u16*)d_out + (size_t)N * 64;   // N*64 bf16

    // --- ws layout ---
    u16*  t3b = (u16*)d_ws;                    // N*64 bf16
    int2* stg = (int2*)d_ws;                   // E int2 overlay (build only)
    int*  row_ptr    = (int*)((char*)d_ws + (size_t)N * 64 * 2);  // N+1
    int*  region_off = row_ptr + (N + 1);      // NREG+1
    int*  partial    = region_off + (NREG + 1);// NBLK*256
    size_t wOff = (((size_t)((char*)(partial + NBLK * 256) - (char*)d_ws)) + 15) & ~(size_t)15;
    u16* W1f = (u16*)((char*)d_ws + wOff);     // 2048 bf16
    u16* W2f = W1f + 2048;                     // 4096 bf16
    size_t cvOff = (((size_t)((char*)(W2f + 4096) - (char*)d_ws)) + 15) & ~(size_t)15;
    u32* cv = (u32*)((char*)d_ws + cvOff);     // E packed 4B edges
    size_t barOff = (cvOff + (size_t)E * 4 + 255) & ~(size_t)255;
    int* bar = (int*)((char*)d_ws + barOff);   // [cnt, gen]

    int n4 = (N * 32) / 4;

    // ---- CSR build: single fused kernel, 4 device-scope grid barriers ----
    hipMemsetAsync(bar, 0, 16, stream);
    build_fused_kernel<<<NBLK, 256, 0, stream>>>(
        edge_row, edge_col, edge_val, E, x, xb, n4,
        W1, W2, W1f, W2f, partial, region_off, stg, row_ptr, cv, N, NREG, bar);

    // ---- pipeline ----
    int g32 = (N * 4 + 255) / 256;   // D=32: 4 lanes/row (also 64 rows/block)
    int g64 = (N * 8 + 255) / 256;   // D=64: 8 lanes/row

    spmm_bf16_kernel<32, false><<<g32, 256, 0, stream>>>(xb, row_ptr, cv, t0b, nullptr, N);
    spmm_dense_kernel<<<g32, 256, 0, stream>>>(t0b, row_ptr, cv, W1f, b1, W2f, t2b, N);
    spmm_bf16_kernel<64, false><<<g64, 256, 0, stream>>>(t2b, row_ptr, cv, t3b, nullptr, N);
    spmm_bf16_kernel<64, true><<<g64, 256, 0, stream>>>(t3b, row_ptr, cv, out, b2, N);
}

// Round 8
// 282.303 us; speedup vs baseline: 1.5958x; 1.5958x over previous
//
#include <hip/hip_runtime.h>
#include <hip/hip_bf16.h>

// GCN: h = (0.5A)^2 x ; h = relu(h W1 + b1) ; h = (0.5A)^2 h ; h = h W2 + b2
// r20: RESUBMIT of r19 (infra "container failed twice", no kernel signal).
// r19: shrink CSR build WITHOUT grid-sync (r18 lesson: device-scope barriers
//  cost >>dispatch overhead on multi-XCD CDNA4; fused build ran 269us alone,
//  idle-spinning on L2 writeback/invalidate). r18 also showed build+gaps
//  ~103us of r17's 284 -> worth attacking via dispatch merge + traffic cuts:
//   - K2a+K2b merged into K2m (196 blocks): block r recomputes region_off[r]
//     from partial rows (contiguous per-thread slices, LDS reduce) and writes
//     scatter bases to a SEPARATE bases[] array (no read/write race).
//   - stg slimmed 8->6 B/edge: stgk u32 (col|lrow<<17) + stgv u16 (val bits).
//   - K4 stages its region's edges into LDS once (cap 9216, global fallback)
//     instead of two global passes over stg.
//  S-kernels byte-identical to r17 (284.2us).
// Kernels: K1 convert+hist+wfrag, K2m scan+base, K3 coarse scatter,
//          K4 region sort (LDS-staged), S1, S2f, S3, S4.  (8 total)
// Buffers (d_out used as raw scratch until final write):
//  xb  = d_out[0,6.4MB)   t0b = d_out[6.4,12.8MB)   t2b = d_out[12.8,25.6MB)
//  ws: t3b[0,12.8MB) (stgk/stgv overlay, dead by K4 end) | row_ptr N+1 |
//      region_off NREG+1 | partial G*256 | bases G*256 | W1f 4KB | W2f 8KB |
//      cv E*4B

#define REGION_SHIFT 9               // 512 rows per region
#define REGION_SIZE  (1 << REGION_SHIFT)
#define COL_MASK 0x1FFFF             // 17 bits, N=100000 < 131072
#define GBUILD 256                   // blocks for K1/K3 (chunking must match!)
#define K4CAP 9216                   // LDS-staged edges/region (avg 8163)

typedef unsigned short u16;
typedef unsigned int   u32;
typedef __attribute__((ext_vector_type(8))) short bf16x8;
typedef __attribute__((ext_vector_type(4))) float f32x4;

__device__ inline float bflo(u32 w) { return __uint_as_float(w << 16); }
__device__ inline float bfhi(u32 w) { return __uint_as_float(w & 0xffff0000u); }
// pack two fp32 -> bf16 pair (RTN-even), a in low half
__device__ inline u32 bfpack(float a, float b) {
    u32 ua = __float_as_uint(a), ub = __float_as_uint(b);
    ua = (ua + 0x7fffu + ((ua >> 16) & 1u)) >> 16;
    ub = (ub + 0x7fffu + ((ub >> 16) & 1u)) & 0xffff0000u;
    return ua | ub;
}
__device__ inline u16 bf1(float f) {
    u32 u = __float_as_uint(f);
    return (u16)((u + 0x7fffu + ((u >> 16) & 1u)) >> 16);
}

// ---- K1: fp32->bf16 convert + per-block LDS region hist + weight frags ----
__global__ void region_count_kernel(const int* __restrict__ er, int E,
                                    int* __restrict__ partial,
                                    const float* __restrict__ x,
                                    u16* __restrict__ xb, int n4,
                                    const float* __restrict__ W1,
                                    const float* __restrict__ W2,
                                    u16* __restrict__ W1f,
                                    u16* __restrict__ W2f) {
    for (int i = blockIdx.x * 256 + threadIdx.x; i < n4; i += gridDim.x * 256) {
        float4 a = reinterpret_cast<const float4*>(x)[i];
        uint2 o;
        o.x = bfpack(a.x, a.y);
        o.y = bfpack(a.z, a.w);
        reinterpret_cast<uint2*>(xb)[i] = o;
    }
    if (blockIdx.x == 0) {
        // W1f[t][quad][n16][j] = bf16(W1[(quad*8+j)*64 + t*16 + n16])
        for (int idx = threadIdx.x; idx < 2048; idx += 256) {
            int j = idx & 7, n16 = (idx >> 3) & 15;
            int quad = (idx >> 7) & 3, t = (idx >> 9) & 3;
            W1f[idx] = bf1(W1[(quad * 8 + j) * 64 + t * 16 + n16]);
        }
        // W2f[t][half][quad][n16][j] = bf16(W2[(half*32+quad*8+j)*64 + t*16 + n16])
        for (int idx = threadIdx.x; idx < 4096; idx += 256) {
            int j = idx & 7, n16 = (idx >> 3) & 15;
            int quad = (idx >> 7) & 3, half = (idx >> 9) & 1, t = (idx >> 10) & 3;
            W2f[idx] = bf1(W2[(half * 32 + quad * 8 + j) * 64 + t * 16 + n16]);
        }
    }
    __shared__ int hist[256];
    int t = threadIdx.x;
    hist[t] = 0;
    __syncthreads();
    int chunk = (E + gridDim.x - 1) / gridDim.x;
    int s = blockIdx.x * chunk;
    int e = min(E, s + chunk);
    for (int i = s + t; i < e; i += 256)
        atomicAdd(&hist[er[i] >> REGION_SHIFT], 1);
    __syncthreads();
    partial[blockIdx.x * 256 + t] = hist[t];   // single-writer 1KB row
}

// ---- K2m: merged scan+base. Block r: region_off[r] from partial (read-only)
//      + per-block scatter bases for region r -> bases[] (separate array). --
__global__ void region_scanbase_kernel(const int* __restrict__ partial,
                                       int* __restrict__ bases,
                                       int* __restrict__ region_off,
                                       int nreg, int E, int G) {
    __shared__ int s[256];
    int r = blockIdx.x;
    if (r >= nreg) return;
    int t = threadIdx.x;
    // region_off[r] = sum over blocks b, regions q<r of partial[b*256+q]
    int rowsum = 0;
    const int* prow = partial + t * 256;       // thread t = block t's row
    for (int q = 0; q < r; q++) rowsum += prow[q];   // contiguous slice
    s[t] = rowsum;
    __syncthreads();
    for (int off = 128; off > 0; off >>= 1) {
        if (t < off) s[t] += s[t + off];
        __syncthreads();
    }
    int off_r = s[0];
    __syncthreads();
    if (t == 0) {
        region_off[r] = off_r;
        if (r == 0) region_off[nreg] = E;
    }
    // per-block exclusive scan of partial[t*256+r] over t -> bases
    int c = prow[r];
    s[t] = c;
    __syncthreads();
    for (int off = 1; off < 256; off <<= 1) {
        int xv = (t >= off) ? s[t - off] : 0;
        __syncthreads();
        s[t] += xv;
        __syncthreads();
    }
    bases[t * 256 + r] = off_r + s[t] - c;     // exclusive base
}

// ---- K3: coarse scatter, LDS rank only (no global atomics) ----
// stgk: col | localrow<<17 ; stgv: bf16 bits of 0.5*val (15 bits, >=0)
__global__ void coarse_scatter_kernel(const int* __restrict__ er,
                                      const int* __restrict__ ec,
                                      const float* __restrict__ ev, int E,
                                      const int* __restrict__ bases,
                                      u32* __restrict__ stgk,
                                      u16* __restrict__ stgv) {
    __shared__ int cnt2[256], gbase[256];
    int t = threadIdx.x;
    cnt2[t] = 0;
    gbase[t] = bases[blockIdx.x * 256 + t];
    __syncthreads();
    int chunk = (E + gridDim.x - 1) / gridDim.x;   // identical to K1
    int s0 = blockIdx.x * chunk;
    int e0 = min(E, s0 + chunk);
    for (int i = s0 + t; i < e0; i += 256) {
        int r = er[i];
        int b = r >> REGION_SHIFT;
        int rank = atomicAdd(&cnt2[b], 1);
        int p = gbase[b] + rank;                   // block-private run
        stgk[p] = (u32)ec[i] | ((u32)(r & (REGION_SIZE - 1)) << 17);
        stgv[p] = bf1(0.5f * ev[i]);               // positive: 15 bits
    }
}

// ---- K4: per-region LDS-staged sort -> row_ptr + packed 4B cv ----
__global__ void region_sort_kernel(const u32* __restrict__ stgk,
                                   const u16* __restrict__ stgv,
                                   const int* __restrict__ region_off,
                                   int* __restrict__ row_ptr,
                                   u32* __restrict__ cv, int N, int E) {
    __shared__ u32 sk[K4CAP];
    __shared__ u16 sv[K4CAP];
    __shared__ int hist[REGION_SIZE];
    __shared__ int wp_local[REGION_SIZE];
    __shared__ int psum[256];
    int cb = blockIdx.x;
    int lo = cb << REGION_SHIFT;
    if (lo >= N) return;
    int hi = min(lo + REGION_SIZE, N);
    int cnt = hi - lo;
    int t = threadIdx.x;
    for (int r = t; r < cnt; r += 256) hist[r] = 0;
    int start = region_off[cb];
    int end   = region_off[cb + 1];
    // stage region edges into LDS (coalesced, once)
    for (int q = start + t; q < end; q += 256) {
        int idx = q - start;
        if (idx < K4CAP) { sk[idx] = stgk[q]; sv[idx] = stgv[q]; }
    }
    __syncthreads();
    for (int q = start + t; q < end; q += 256) {
        int idx = q - start;
        u32 key = (idx < K4CAP) ? sk[idx] : stgk[q];
        atomicAdd(&hist[key >> 17], 1);
    }
    __syncthreads();
    int a0 = (2 * t     < cnt) ? hist[2 * t]     : 0;
    int a1 = (2 * t + 1 < cnt) ? hist[2 * t + 1] : 0;
    psum[t] = a0 + a1;
    __syncthreads();
    for (int off = 1; off < 256; off <<= 1) {
        int x = (t >= off) ? psum[t - off] : 0;
        __syncthreads();
        psum[t] += x;
        __syncthreads();
    }
    int excl = psum[t] - (a0 + a1);
    if (2 * t < cnt) {
        wp_local[2 * t] = start + excl;
        row_ptr[lo + 2 * t] = start + excl;
    }
    if (2 * t + 1 < cnt) {
        wp_local[2 * t + 1] = start + excl + a0;
        row_ptr[lo + 2 * t + 1] = start + excl + a0;
    }
    if (cb == 0 && t == 0) row_ptr[N] = E;
    __syncthreads();
    for (int q = start + t; q < end; q += 256) {
        int idx = q - start;
        u32 key; u32 val;
        if (idx < K4CAP) { key = sk[idx]; val = sv[idx]; }
        else             { key = stgk[q]; val = stgv[q]; }
        int lr = key >> 17;
        int p = atomicAdd(&wp_local[lr], 1);      // LDS atomic
        cv[p] = (val << 17) | (key & COL_MASK);   // private window
    }
}

// ---------------- CSR SpMM, gather-side, bf16 table / fp32 accum ------------
__device__ inline void fma8(float acc[8], float v, uint4 w) {
    acc[0] = fmaf(v, bflo(w.x), acc[0]); acc[1] = fmaf(v, bfhi(w.x), acc[1]);
    acc[2] = fmaf(v, bflo(w.y), acc[2]); acc[3] = fmaf(v, bfhi(w.y), acc[3]);
    acc[4] = fmaf(v, bflo(w.z), acc[4]); acc[5] = fmaf(v, bfhi(w.z), acc[5]);
    acc[6] = fmaf(v, bflo(w.w), acc[6]); acc[7] = fmaf(v, bfhi(w.w), acc[7]);
}
__device__ inline float cvval(u32 q) { return __uint_as_float((q >> 17) << 16); }

// Shared spmm inner loop: 8 gathers in flight (MLP), then 4-wide, scalar tail.
template <int D>
__device__ inline void spmm_row(const u16* __restrict__ h,
                                const u32* __restrict__ cv,
                                int start, int end, int sub, float acc[8]) {
    int j = start;
    for (; j + 8 <= end; j += 8) {
        u32 q0 = cv[j],     q1 = cv[j + 1], q2 = cv[j + 2], q3 = cv[j + 3];
        u32 q4 = cv[j + 4], q5 = cv[j + 5], q6 = cv[j + 6], q7 = cv[j + 7];
        uint4 w0 = reinterpret_cast<const uint4*>(h + (size_t)(q0 & COL_MASK) * D)[sub];
        uint4 w1 = reinterpret_cast<const uint4*>(h + (size_t)(q1 & COL_MASK) * D)[sub];
        uint4 w2 = reinterpret_cast<const uint4*>(h + (size_t)(q2 & COL_MASK) * D)[sub];
        uint4 w3 = reinterpret_cast<const uint4*>(h + (size_t)(q3 & COL_MASK) * D)[sub];
        uint4 w4 = reinterpret_cast<const uint4*>(h + (size_t)(q4 & COL_MASK) * D)[sub];
        uint4 w5 = reinterpret_cast<const uint4*>(h + (size_t)(q5 & COL_MASK) * D)[sub];
        uint4 w6 = reinterpret_cast<const uint4*>(h + (size_t)(q6 & COL_MASK) * D)[sub];
        uint4 w7 = reinterpret_cast<const uint4*>(h + (size_t)(q7 & COL_MASK) * D)[sub];
        fma8(acc, cvval(q0), w0);
        fma8(acc, cvval(q1), w1);
        fma8(acc, cvval(q2), w2);
        fma8(acc, cvval(q3), w3);
        fma8(acc, cvval(q4), w4);
        fma8(acc, cvval(q5), w5);
        fma8(acc, cvval(q6), w6);
        fma8(acc, cvval(q7), w7);
    }
    for (; j + 4 <= end; j += 4) {
        u32 q0 = cv[j], q1 = cv[j + 1], q2 = cv[j + 2], q3 = cv[j + 3];
        uint4 w0 = reinterpret_cast<const uint4*>(h + (size_t)(q0 & COL_MASK) * D)[sub];
        uint4 w1 = reinterpret_cast<const uint4*>(h + (size_t)(q1 & COL_MASK) * D)[sub];
        uint4 w2 = reinterpret_cast<const uint4*>(h + (size_t)(q2 & COL_MASK) * D)[sub];
        uint4 w3 = reinterpret_cast<const uint4*>(h + (size_t)(q3 & COL_MASK) * D)[sub];
        fma8(acc, cvval(q0), w0);
        fma8(acc, cvval(q1), w1);
        fma8(acc, cvval(q2), w2);
        fma8(acc, cvval(q3), w3);
    }
    for (; j < end; j++) {
        u32 q = cv[j];
        uint4 w = reinterpret_cast<const uint4*>(h + (size_t)(q & COL_MASK) * D)[sub];
        fma8(acc, cvval(q), w);
    }
}

// D features/row; 8 features (16B) per lane; LPR = D/8 lanes per row.
template <int D, bool FINAL>
__global__ __launch_bounds__(256) void spmm_bf16_kernel(
        const u16* __restrict__ h,
        const int* __restrict__ row_ptr,
        const u32* __restrict__ cv,
        void* __restrict__ outp,
        const float* __restrict__ bias,  // used iff FINAL
        int N) {
    constexpr int LPR = D / 8;
    int gid = blockIdx.x * 256 + threadIdx.x;
    int row = gid / LPR;
    int sub = gid % LPR;
    if (row >= N) return;
    int start = row_ptr[row];
    int end   = row_ptr[row + 1];
    float acc[8] = {0.f, 0.f, 0.f, 0.f, 0.f, 0.f, 0.f, 0.f};
    spmm_row<D>(h, cv, start, end, sub, acc);
    if (FINAL) {
        float* op = (float*)outp + (size_t)row * 64 + sub * 8;
#pragma unroll
        for (int k = 0; k < 8; k++) acc[k] += bias[sub * 8 + k];
        reinterpret_cast<float4*>(op)[0] = make_float4(acc[0], acc[1], acc[2], acc[3]);
        reinterpret_cast<float4*>(op)[1] = make_float4(acc[4], acc[5], acc[6], acc[7]);
    } else {
        u16* ob = (u16*)outp + (size_t)row * D + sub * 8;
        uint4 o;
        o.x = bfpack(acc[0], acc[1]);
        o.y = bfpack(acc[2], acc[3]);
        o.z = bfpack(acc[4], acc[5]);
        o.w = bfpack(acc[6], acc[7]);
        reinterpret_cast<uint4*>(ob)[0] = o;
    }
}

// ---- S2f: spmm32 + dense fused: t2 = relu(spmm(t0)@W1 + b1) @ W2 ----------
// Block = 256 thr = 4 waves; LPR=4 -> 64 rows/block = one 16-row tile/wave.
// spmm acc -> LDS tile (bf16) -> per-wave 16x16x32 MFMA (verified r10 layout).
__global__ __launch_bounds__(256) void spmm_dense_kernel(
        const u16* __restrict__ h,       // t0b [N,32] bf16
        const int* __restrict__ row_ptr,
        const u32* __restrict__ cv,
        const u16* __restrict__ W1f,     // [4][4][16][8] bf16 frags
        const float* __restrict__ b1,    // [64]
        const u16* __restrict__ W2f,     // [4][2][4][16][8] bf16 frags
        u16* __restrict__ outb,          // t2b [N,64] bf16
        int N) {
    __shared__ __align__(16) u16 tiles[4][16][80];   // pad 80 (160B = 16B-mult)
    int tid = threadIdx.x;
    int lane = tid & 63;
    int wave = tid >> 6;
    int tilebase = blockIdx.x * 64 + wave * 16;
    if (tilebase >= N) return;           // wave-uniform (N % 16 == 0)
    int gid = blockIdx.x * 256 + tid;
    int row = gid >> 2;                  // LPR = 4
    int sub = gid & 3;

    // ---- spmm D=32 ----
    bool vr = row < N;
    int start = vr ? row_ptr[row] : 0;
    int end   = vr ? row_ptr[row + 1] : 0;
    float acc[8] = {0.f, 0.f, 0.f, 0.f, 0.f, 0.f, 0.f, 0.f};
    spmm_row<32>(h, cv, start, end, sub, acc);

    // ---- stash t1 tile in LDS as bf16 (per-wave private; in-order DS) ----
    u16 (*tile)[80] = tiles[wave];
    {
        uint4 o;
        o.x = bfpack(acc[0], acc[1]);
        o.y = bfpack(acc[2], acc[3]);
        o.z = bfpack(acc[4], acc[5]);
        o.w = bfpack(acc[6], acc[7]);
        *reinterpret_cast<uint4*>(&tile[lane >> 2][sub * 8]) = o;
    }

    // ---- dense: relu(t1@W1+b1)@W2 on MFMA 16x16x32 (verified r10 layout) --
    int n16 = lane & 15;
    int quad = lane >> 4;
    bf16x8 w1f[4];
    bf16x8 w2f[4][2];
#pragma unroll
    for (int t = 0; t < 4; t++) {
        w1f[t] = *reinterpret_cast<const bf16x8*>(&W1f[((t * 4 + quad) * 16 + n16) * 8]);
        w2f[t][0] = *reinterpret_cast<const bf16x8*>(&W2f[(((t * 2 + 0) * 4 + quad) * 16 + n16) * 8]);
        w2f[t][1] = *reinterpret_cast<const bf16x8*>(&W2f[(((t * 2 + 1) * 4 + quad) * 16 + n16) * 8]);
    }
    float b1v[4];
#pragma unroll
    for (int t = 0; t < 4; t++) b1v[t] = b1[t * 16 + n16];

    bf16x8 a1 = *reinterpret_cast<const bf16x8*>(&tile[n16][quad * 8]);
    f32x4 zero = {0.f, 0.f, 0.f, 0.f};
    f32x4 c[4];
#pragma unroll
    for (int t = 0; t < 4; t++)
        c[t] = __builtin_amdgcn_mfma_f32_16x16x32_bf16(a1, w1f[t], zero, 0, 0, 0);

#pragma unroll
    for (int t = 0; t < 4; t++)
#pragma unroll
        for (int i = 0; i < 4; i++)
            tile[quad * 4 + i][t * 16 + n16] = bf1(fmaxf(c[t][i] + b1v[t], 0.f));

    bf16x8 a2_0 = *reinterpret_cast<const bf16x8*>(&tile[n16][quad * 8]);
    bf16x8 a2_1 = *reinterpret_cast<const bf16x8*>(&tile[n16][32 + quad * 8]);
    f32x4 d[4];
#pragma unroll
    for (int t = 0; t < 4; t++) {
        d[t] = __builtin_amdgcn_mfma_f32_16x16x32_bf16(a2_0, w2f[t][0], zero, 0, 0, 0);
        d[t] = __builtin_amdgcn_mfma_f32_16x16x32_bf16(a2_1, w2f[t][1], d[t], 0, 0, 0);
    }

#pragma unroll
    for (int t = 0; t < 4; t++)
#pragma unroll
        for (int i = 0; i < 4; i++)
            tile[quad * 4 + i][t * 16 + n16] = bf1(d[t][i]);

#pragma unroll
    for (int half = 0; half < 2; half++) {
        int g = half * 512 + lane * 8;
        int r = g >> 6, cc = g & 63;
        int grow = tilebase + r;
        if (grow < N)
            *reinterpret_cast<uint4*>(outb + (size_t)grow * 64 + cc) =
                *reinterpret_cast<const uint4*>(&tile[r][cc]);
    }
}

extern "C" void kernel_launch(void* const* d_in, const int* in_sizes, int n_in,
                              void* d_out, int out_size, void* d_ws, size_t ws_size,
                              hipStream_t stream) {
    const float* x        = (const float*)d_in[0];
    const float* edge_val = (const float*)d_in[1];
    const int*   edge_row = (const int*)d_in[2];
    const int*   edge_col = (const int*)d_in[3];
    const float* W1       = (const float*)d_in[4];
    const float* b1       = (const float*)d_in[5];
    const float* W2       = (const float*)d_in[6];
    const float* b2       = (const float*)d_in[7];
    float* out = (float*)d_out;

    const int N = in_sizes[0] / 32;   // 100000
    const int E = in_sizes[1];        // 1600000
    const int NREG = (N + REGION_SIZE - 1) >> REGION_SHIFT;  // 196

    // --- d_out as raw scratch (fp32 final write overwrites all) ---
    u16* xb  = (u16*)d_out;                    // N*32 bf16
    u16* t0b = xb + (size_t)N * 32;            // N*32 bf16
    u16* t2b = (u16*)d_out + (size_t)N * 64;   // N*64 bf16

    // --- ws layout ---
    u16* t3b  = (u16*)d_ws;                    // N*64 bf16
    u32* stgk = (u32*)d_ws;                    // E u32 overlay (build only)
    u16* stgv = (u16*)((char*)d_ws + (size_t)E * 4);  // E u16 overlay
    int* row_ptr    = (int*)((char*)d_ws + (size_t)N * 64 * 2);  // N+1
    int* region_off = row_ptr + (N + 1);       // NREG+1
    int* partial    = region_off + (NREG + 1); // GBUILD*256
    int* bases      = partial + GBUILD * 256;  // GBUILD*256
    size_t wOff = (((size_t)((char*)(bases + GBUILD * 256) - (char*)d_ws)) + 15) & ~(size_t)15;
    u16* W1f = (u16*)((char*)d_ws + wOff);     // 2048 bf16
    u16* W2f = W1f + 2048;                     // 4096 bf16
    size_t cvOff = (((size_t)((char*)(W2f + 4096) - (char*)d_ws)) + 15) & ~(size_t)15;
    u32* cv = (u32*)((char*)d_ws + cvOff);     // E packed 4B edges

    int n4 = (N * 32) / 4;

    // ---- CSR build (2-pass radix, zero global atomics, no memset) ----
    region_count_kernel<<<GBUILD, 256, 0, stream>>>(edge_row, E, partial, x, xb, n4,
                                                    W1, W2, W1f, W2f);
    region_scanbase_kernel<<<NREG, 256, 0, stream>>>(partial, bases, region_off,
                                                     NREG, E, GBUILD);
    coarse_scatter_kernel<<<GBUILD, 256, 0, stream>>>(edge_row, edge_col, edge_val,
                                                      E, bases, stgk, stgv);
    region_sort_kernel<<<NREG, 256, 0, stream>>>(stgk, stgv, region_off,
                                                 row_ptr, cv, N, E);

    // ---- pipeline ----
    int g32 = (N * 4 + 255) / 256;   // D=32: 4 lanes/row (also 64 rows/block)
    int g64 = (N * 8 + 255) / 256;   // D=64: 8 lanes/row

    spmm_bf16_kernel<32, false><<<g32, 256, 0, stream>>>(xb, row_ptr, cv, t0b, nullptr, N);
    spmm_dense_kernel<<<g32, 256, 0, stream>>>(t0b, row_ptr, cv, W1f, b1, W2f, t2b, N);
    spmm_bf16_kernel<64, false><<<g64, 256, 0, stream>>>(t2b, row_ptr, cv, t3b, nullptr, N);
    spmm_bf16_kernel<64, true><<<g64, 256, 0, stream>>>(t3b, row_ptr, cv, out, b2, N);
}

// Round 9
// 279.743 us; speedup vs baseline: 1.6104x; 1.0092x over previous
//
#include <hip/hip_runtime.h>
#include <hip/hip_bf16.h>

// GCN: h = (0.5A)^2 x ; h = relu(h W1 + b1) ; h = (0.5A)^2 h ; h = h W2 + b2
// r21: column-phase-sorted CSR for L2-resident gather windows.
//  r20 (282.3us) showed build micro-opts exhausted; spmm chain (~170us) does
//  614MB of random gathers into 6.4-12.8MB tables -> served by L3 (tables >
//  4MB/XCD L2) at ~600-900cy. Fix: K4 sorts each row's edges by 3-bit column
//  phase (col>>14, key = lrow<<3 | ph, 4096-key LDS counting sort). All waves
//  start at phase 0 together -> co-resident waves gather from a moving
//  ~1-2MB/phase column window that FITS per-XCD L2. Within-row order is a
//  permutation (sums commute); row_ptr semantics unchanged (prefix at r*8).
//  K4's LDS edge staging dropped (r20 proved ~noise); LDS now 17KB.
//  All other kernels byte-identical to r20.
// Kernels: K1 convert+hist+wfrag, K2m scan+base, K3 coarse scatter,
//          K4 phase sort, S1, S2f, S3, S4.  (8 total)
// Buffers (d_out used as raw scratch until final write):
//  xb  = d_out[0,6.4MB)   t0b = d_out[6.4,12.8MB)   t2b = d_out[12.8,25.6MB)
//  ws: t3b[0,12.8MB) (stgk/stgv overlay, dead by K4 end) | row_ptr N+1 |
//      region_off NREG+1 | partial G*256 | bases G*256 | W1f 4KB | W2f 8KB |
//      cv E*4B

#define REGION_SHIFT 9               // 512 rows per region
#define REGION_SIZE  (1 << REGION_SHIFT)
#define COL_MASK 0x1FFFF             // 17 bits, N=100000 < 131072
#define GBUILD 256                   // blocks for K1/K3 (chunking must match!)
#define NPH_SHIFT 3                  // 8 column phases (col>>14: 0..6 used)
#define NKEY (REGION_SIZE << NPH_SHIFT)  // 4096 sort keys

typedef unsigned short u16;
typedef unsigned int   u32;
typedef __attribute__((ext_vector_type(8))) short bf16x8;
typedef __attribute__((ext_vector_type(4))) float f32x4;

__device__ inline float bflo(u32 w) { return __uint_as_float(w << 16); }
__device__ inline float bfhi(u32 w) { return __uint_as_float(w & 0xffff0000u); }
// pack two fp32 -> bf16 pair (RTN-even), a in low half
__device__ inline u32 bfpack(float a, float b) {
    u32 ua = __float_as_uint(a), ub = __float_as_uint(b);
    ua = (ua + 0x7fffu + ((ua >> 16) & 1u)) >> 16;
    ub = (ub + 0x7fffu + ((ub >> 16) & 1u)) & 0xffff0000u;
    return ua | ub;
}
__device__ inline u16 bf1(float f) {
    u32 u = __float_as_uint(f);
    return (u16)((u + 0x7fffu + ((u >> 16) & 1u)) >> 16);
}

// ---- K1: fp32->bf16 convert + per-block LDS region hist + weight frags ----
__global__ void region_count_kernel(const int* __restrict__ er, int E,
                                    int* __restrict__ partial,
                                    const float* __restrict__ x,
                                    u16* __restrict__ xb, int n4,
                                    const float* __restrict__ W1,
                                    const float* __restrict__ W2,
                                    u16* __restrict__ W1f,
                                    u16* __restrict__ W2f) {
    for (int i = blockIdx.x * 256 + threadIdx.x; i < n4; i += gridDim.x * 256) {
        float4 a = reinterpret_cast<const float4*>(x)[i];
        uint2 o;
        o.x = bfpack(a.x, a.y);
        o.y = bfpack(a.z, a.w);
        reinterpret_cast<uint2*>(xb)[i] = o;
    }
    if (blockIdx.x == 0) {
        // W1f[t][quad][n16][j] = bf16(W1[(quad*8+j)*64 + t*16 + n16])
        for (int idx = threadIdx.x; idx < 2048; idx += 256) {
            int j = idx & 7, n16 = (idx >> 3) & 15;
            int quad = (idx >> 7) & 3, t = (idx >> 9) & 3;
            W1f[idx] = bf1(W1[(quad * 8 + j) * 64 + t * 16 + n16]);
        }
        // W2f[t][half][quad][n16][j] = bf16(W2[(half*32+quad*8+j)*64 + t*16 + n16])
        for (int idx = threadIdx.x; idx < 4096; idx += 256) {
            int j = idx & 7, n16 = (idx >> 3) & 15;
            int quad = (idx >> 7) & 3, half = (idx >> 9) & 1, t = (idx >> 10) & 3;
            W2f[idx] = bf1(W2[(half * 32 + quad * 8 + j) * 64 + t * 16 + n16]);
        }
    }
    __shared__ int hist[256];
    int t = threadIdx.x;
    hist[t] = 0;
    __syncthreads();
    int chunk = (E + gridDim.x - 1) / gridDim.x;
    int s = blockIdx.x * chunk;
    int e = min(E, s + chunk);
    for (int i = s + t; i < e; i += 256)
        atomicAdd(&hist[er[i] >> REGION_SHIFT], 1);
    __syncthreads();
    partial[blockIdx.x * 256 + t] = hist[t];   // single-writer 1KB row
}

// ---- K2m: merged scan+base. Block r: region_off[r] from partial (read-only)
//      + per-block scatter bases for region r -> bases[] (separate array). --
__global__ void region_scanbase_kernel(const int* __restrict__ partial,
                                       int* __restrict__ bases,
                                       int* __restrict__ region_off,
                                       int nreg, int E, int G) {
    __shared__ int s[256];
    int r = blockIdx.x;
    if (r >= nreg) return;
    int t = threadIdx.x;
    // region_off[r] = sum over blocks b, regions q<r of partial[b*256+q]
    int rowsum = 0;
    const int* prow = partial + t * 256;       // thread t = block t's row
    for (int q = 0; q < r; q++) rowsum += prow[q];   // contiguous slice
    s[t] = rowsum;
    __syncthreads();
    for (int off = 128; off > 0; off >>= 1) {
        if (t < off) s[t] += s[t + off];
        __syncthreads();
    }
    int off_r = s[0];
    __syncthreads();
    if (t == 0) {
        region_off[r] = off_r;
        if (r == 0) region_off[nreg] = E;
    }
    // per-block exclusive scan of partial[t*256+r] over t -> bases
    int c = prow[r];
    s[t] = c;
    __syncthreads();
    for (int off = 1; off < 256; off <<= 1) {
        int xv = (t >= off) ? s[t - off] : 0;
        __syncthreads();
        s[t] += xv;
        __syncthreads();
    }
    bases[t * 256 + r] = off_r + s[t] - c;     // exclusive base
}

// ---- K3: coarse scatter, LDS rank only (no global atomics) ----
// stgk: col | localrow<<17 ; stgv: bf16 bits of 0.5*val (15 bits, >=0)
__global__ void coarse_scatter_kernel(const int* __restrict__ er,
                                      const int* __restrict__ ec,
                                      const float* __restrict__ ev, int E,
                                      const int* __restrict__ bases,
                                      u32* __restrict__ stgk,
                                      u16* __restrict__ stgv) {
    __shared__ int cnt2[256], gbase[256];
    int t = threadIdx.x;
    cnt2[t] = 0;
    gbase[t] = bases[blockIdx.x * 256 + t];
    __syncthreads();
    int chunk = (E + gridDim.x - 1) / gridDim.x;   // identical to K1
    int s0 = blockIdx.x * chunk;
    int e0 = min(E, s0 + chunk);
    for (int i = s0 + t; i < e0; i += 256) {
        int r = er[i];
        int b = r >> REGION_SHIFT;
        int rank = atomicAdd(&cnt2[b], 1);
        int p = gbase[b] + rank;                   // block-private run
        stgk[p] = (u32)ec[i] | ((u32)(r & (REGION_SIZE - 1)) << 17);
        stgv[p] = bf1(0.5f * ev[i]);               // positive: 15 bits
    }
}

// ---- K4: per-region LDS counting sort by (localrow, col-phase) ------------
// key = lrow<<3 | (col>>14). Row r's edges = keys [r*8,(r+1)*8) contiguous,
// phase-ordered -> row_ptr[row] = prefix at key r*8. hist doubles as wp.
__global__ void region_sort_kernel(const u32* __restrict__ stgk,
                                   const u16* __restrict__ stgv,
                                   const int* __restrict__ region_off,
                                   int* __restrict__ row_ptr,
                                   u32* __restrict__ cv, int N, int E) {
    __shared__ int hist[NKEY];      // counts -> exclusive prefix -> wp
    __shared__ int psum[256];
    int cb = blockIdx.x;
    int lo = cb << REGION_SHIFT;
    if (lo >= N) return;
    int hi = min(lo + REGION_SIZE, N);
    int cnt = hi - lo;
    int t = threadIdx.x;
    for (int k = t; k < NKEY; k += 256) hist[k] = 0;
    __syncthreads();
    int start = region_off[cb];
    int end   = region_off[cb + 1];
    for (int q = start + t; q < end; q += 256) {
        u32 key = stgk[q];
        int lr = key >> 17;
        int ph = (int)((key & COL_MASK) >> 14);    // 0..6
        atomicAdd(&hist[(lr << NPH_SHIFT) | ph], 1);
    }
    __syncthreads();
    // block-wide exclusive scan of hist[0..NKEY): 16 keys/thread
    int base_t = t * 16;
    int vals[16];
    int local = 0;
#pragma unroll
    for (int k = 0; k < 16; k++) { vals[k] = hist[base_t + k]; local += vals[k]; }
    psum[t] = local;
    __syncthreads();
    for (int off = 1; off < 256; off <<= 1) {
        int xv = (t >= off) ? psum[t - off] : 0;
        __syncthreads();
        psum[t] += xv;
        __syncthreads();
    }
    int run = start + psum[t] - local;             // global exclusive offset
#pragma unroll
    for (int k = 0; k < 16; k++) { hist[base_t + k] = run; run += vals[k]; }
    __syncthreads();
    // row_ptr from prefixes (before scatter destroys them)
    for (int r = t; r < cnt; r += 256)
        row_ptr[lo + r] = hist[r << NPH_SHIFT];
    if (cb == 0 && t == 0) row_ptr[N] = E;
    __syncthreads();
    // scatter (hist now serves as running write pointers)
    for (int q = start + t; q < end; q += 256) {
        u32 key = stgk[q];
        u32 val = stgv[q];
        int lr = key >> 17;
        int ph = (int)((key & COL_MASK) >> 14);
        int p = atomicAdd(&hist[(lr << NPH_SHIFT) | ph], 1);   // LDS atomic
        cv[p] = (val << 17) | (key & COL_MASK);
    }
}

// ---------------- CSR SpMM, gather-side, bf16 table / fp32 accum ------------
__device__ inline void fma8(float acc[8], float v, uint4 w) {
    acc[0] = fmaf(v, bflo(w.x), acc[0]); acc[1] = fmaf(v, bfhi(w.x), acc[1]);
    acc[2] = fmaf(v, bflo(w.y), acc[2]); acc[3] = fmaf(v, bfhi(w.y), acc[3]);
    acc[4] = fmaf(v, bflo(w.z), acc[4]); acc[5] = fmaf(v, bfhi(w.z), acc[5]);
    acc[6] = fmaf(v, bflo(w.w), acc[6]); acc[7] = fmaf(v, bfhi(w.w), acc[7]);
}
__device__ inline float cvval(u32 q) { return __uint_as_float((q >> 17) << 16); }

// Shared spmm inner loop: 8 gathers in flight (MLP), then 4-wide, scalar tail.
template <int D>
__device__ inline void spmm_row(const u16* __restrict__ h,
                                const u32* __restrict__ cv,
                                int start, int end, int sub, float acc[8]) {
    int j = start;
    for (; j + 8 <= end; j += 8) {
        u32 q0 = cv[j],     q1 = cv[j + 1], q2 = cv[j + 2], q3 = cv[j + 3];
        u32 q4 = cv[j + 4], q5 = cv[j + 5], q6 = cv[j + 6], q7 = cv[j + 7];
        uint4 w0 = reinterpret_cast<const uint4*>(h + (size_t)(q0 & COL_MASK) * D)[sub];
        uint4 w1 = reinterpret_cast<const uint4*>(h + (size_t)(q1 & COL_MASK) * D)[sub];
        uint4 w2 = reinterpret_cast<const uint4*>(h + (size_t)(q2 & COL_MASK) * D)[sub];
        uint4 w3 = reinterpret_cast<const uint4*>(h + (size_t)(q3 & COL_MASK) * D)[sub];
        uint4 w4 = reinterpret_cast<const uint4*>(h + (size_t)(q4 & COL_MASK) * D)[sub];
        uint4 w5 = reinterpret_cast<const uint4*>(h + (size_t)(q5 & COL_MASK) * D)[sub];
        uint4 w6 = reinterpret_cast<const uint4*>(h + (size_t)(q6 & COL_MASK) * D)[sub];
        uint4 w7 = reinterpret_cast<const uint4*>(h + (size_t)(q7 & COL_MASK) * D)[sub];
        fma8(acc, cvval(q0), w0);
        fma8(acc, cvval(q1), w1);
        fma8(acc, cvval(q2), w2);
        fma8(acc, cvval(q3), w3);
        fma8(acc, cvval(q4), w4);
        fma8(acc, cvval(q5), w5);
        fma8(acc, cvval(q6), w6);
        fma8(acc, cvval(q7), w7);
    }
    for (; j + 4 <= end; j += 4) {
        u32 q0 = cv[j], q1 = cv[j + 1], q2 = cv[j + 2], q3 = cv[j + 3];
        uint4 w0 = reinterpret_cast<const uint4*>(h + (size_t)(q0 & COL_MASK) * D)[sub];
        uint4 w1 = reinterpret_cast<const uint4*>(h + (size_t)(q1 & COL_MASK) * D)[sub];
        uint4 w2 = reinterpret_cast<const uint4*>(h + (size_t)(q2 & COL_MASK) * D)[sub];
        uint4 w3 = reinterpret_cast<const uint4*>(h + (size_t)(q3 & COL_MASK) * D)[sub];
        fma8(acc, cvval(q0), w0);
        fma8(acc, cvval(q1), w1);
        fma8(acc, cvval(q2), w2);
        fma8(acc, cvval(q3), w3);
    }
    for (; j < end; j++) {
        u32 q = cv[j];
        uint4 w = reinterpret_cast<const uint4*>(h + (size_t)(q & COL_MASK) * D)[sub];
        fma8(acc, cvval(q), w);
    }
}

// D features/row; 8 features (16B) per lane; LPR = D/8 lanes per row.
template <int D, bool FINAL>
__global__ __launch_bounds__(256) void spmm_bf16_kernel(
        const u16* __restrict__ h,
        const int* __restrict__ row_ptr,
        const u32* __restrict__ cv,
        void* __restrict__ outp,
        const float* __restrict__ bias,  // used iff FINAL
        int N) {
    constexpr int LPR = D / 8;
    int gid = blockIdx.x * 256 + threadIdx.x;
    int row = gid / LPR;
    int sub = gid % LPR;
    if (row >= N) return;
    int start = row_ptr[row];
    int end   = row_ptr[row + 1];
    float acc[8] = {0.f, 0.f, 0.f, 0.f, 0.f, 0.f, 0.f, 0.f};
    spmm_row<D>(h, cv, start, end, sub, acc);
    if (FINAL) {
        float* op = (float*)outp + (size_t)row * 64 + sub * 8;
#pragma unroll
        for (int k = 0; k < 8; k++) acc[k] += bias[sub * 8 + k];
        reinterpret_cast<float4*>(op)[0] = make_float4(acc[0], acc[1], acc[2], acc[3]);
        reinterpret_cast<float4*>(op)[1] = make_float4(acc[4], acc[5], acc[6], acc[7]);
    } else {
        u16* ob = (u16*)outp + (size_t)row * D + sub * 8;
        uint4 o;
        o.x = bfpack(acc[0], acc[1]);
        o.y = bfpack(acc[2], acc[3]);
        o.z = bfpack(acc[4], acc[5]);
        o.w = bfpack(acc[6], acc[7]);
        reinterpret_cast<uint4*>(ob)[0] = o;
    }
}

// ---- S2f: spmm32 + dense fused: t2 = relu(spmm(t0)@W1 + b1) @ W2 ----------
// Block = 256 thr = 4 waves; LPR=4 -> 64 rows/block = one 16-row tile/wave.
// spmm acc -> LDS tile (bf16) -> per-wave 16x16x32 MFMA (verified r10 layout).
__global__ __launch_bounds__(256) void spmm_dense_kernel(
        const u16* __restrict__ h,       // t0b [N,32] bf16
        const int* __restrict__ row_ptr,
        const u32* __restrict__ cv,
        const u16* __restrict__ W1f,     // [4][4][16][8] bf16 frags
        const float* __restrict__ b1,    // [64]
        const u16* __restrict__ W2f,     // [4][2][4][16][8] bf16 frags
        u16* __restrict__ outb,          // t2b [N,64] bf16
        int N) {
    __shared__ __align__(16) u16 tiles[4][16][80];   // pad 80 (160B = 16B-mult)
    int tid = threadIdx.x;
    int lane = tid & 63;
    int wave = tid >> 6;
    int tilebase = blockIdx.x * 64 + wave * 16;
    if (tilebase >= N) return;           // wave-uniform (N % 16 == 0)
    int gid = blockIdx.x * 256 + tid;
    int row = gid >> 2;                  // LPR = 4
    int sub = gid & 3;

    // ---- spmm D=32 ----
    bool vr = row < N;
    int start = vr ? row_ptr[row] : 0;
    int end   = vr ? row_ptr[row + 1] : 0;
    float acc[8] = {0.f, 0.f, 0.f, 0.f, 0.f, 0.f, 0.f, 0.f};
    spmm_row<32>(h, cv, start, end, sub, acc);

    // ---- stash t1 tile in LDS as bf16 (per-wave private; in-order DS) ----
    u16 (*tile)[80] = tiles[wave];
    {
        uint4 o;
        o.x = bfpack(acc[0], acc[1]);
        o.y = bfpack(acc[2], acc[3]);
        o.z = bfpack(acc[4], acc[5]);
        o.w = bfpack(acc[6], acc[7]);
        *reinterpret_cast<uint4*>(&tile[lane >> 2][sub * 8]) = o;
    }

    // ---- dense: relu(t1@W1+b1)@W2 on MFMA 16x16x32 (verified r10 layout) --
    int n16 = lane & 15;
    int quad = lane >> 4;
    bf16x8 w1f[4];
    bf16x8 w2f[4][2];
#pragma unroll
    for (int t = 0; t < 4; t++) {
        w1f[t] = *reinterpret_cast<const bf16x8*>(&W1f[((t * 4 + quad) * 16 + n16) * 8]);
        w2f[t][0] = *reinterpret_cast<const bf16x8*>(&W2f[(((t * 2 + 0) * 4 + quad) * 16 + n16) * 8]);
        w2f[t][1] = *reinterpret_cast<const bf16x8*>(&W2f[(((t * 2 + 1) * 4 + quad) * 16 + n16) * 8]);
    }
    float b1v[4];
#pragma unroll
    for (int t = 0; t < 4; t++) b1v[t] = b1[t * 16 + n16];

    bf16x8 a1 = *reinterpret_cast<const bf16x8*>(&tile[n16][quad * 8]);
    f32x4 zero = {0.f, 0.f, 0.f, 0.f};
    f32x4 c[4];
#pragma unroll
    for (int t = 0; t < 4; t++)
        c[t] = __builtin_amdgcn_mfma_f32_16x16x32_bf16(a1, w1f[t], zero, 0, 0, 0);

#pragma unroll
    for (int t = 0; t < 4; t++)
#pragma unroll
        for (int i = 0; i < 4; i++)
            tile[quad * 4 + i][t * 16 + n16] = bf1(fmaxf(c[t][i] + b1v[t], 0.f));

    bf16x8 a2_0 = *reinterpret_cast<const bf16x8*>(&tile[n16][quad * 8]);
    bf16x8 a2_1 = *reinterpret_cast<const bf16x8*>(&tile[n16][32 + quad * 8]);
    f32x4 d[4];
#pragma unroll
    for (int t = 0; t < 4; t++) {
        d[t] = __builtin_amdgcn_mfma_f32_16x16x32_bf16(a2_0, w2f[t][0], zero, 0, 0, 0);
        d[t] = __builtin_amdgcn_mfma_f32_16x16x32_bf16(a2_1, w2f[t][1], d[t], 0, 0, 0);
    }

#pragma unroll
    for (int t = 0; t < 4; t++)
#pragma unroll
        for (int i = 0; i < 4; i++)
            tile[quad * 4 + i][t * 16 + n16] = bf1(d[t][i]);

#pragma unroll
    for (int half = 0; half < 2; half++) {
        int g = half * 512 + lane * 8;
        int r = g >> 6, cc = g & 63;
        int grow = tilebase + r;
        if (grow < N)
            *reinterpret_cast<uint4*>(outb + (size_t)grow * 64 + cc) =
                *reinterpret_cast<const uint4*>(&tile[r][cc]);
    }
}

extern "C" void kernel_launch(void* const* d_in, const int* in_sizes, int n_in,
                              void* d_out, int out_size, void* d_ws, size_t ws_size,
                              hipStream_t stream) {
    const float* x        = (const float*)d_in[0];
    const float* edge_val = (const float*)d_in[1];
    const int*   edge_row = (const int*)d_in[2];
    const int*   edge_col = (const int*)d_in[3];
    const float* W1       = (const float*)d_in[4];
    const float* b1       = (const float*)d_in[5];
    const float* W2       = (const float*)d_in[6];
    const float* b2       = (const float*)d_in[7];
    float* out = (float*)d_out;

    const int N = in_sizes[0] / 32;   // 100000
    const int E = in_sizes[1];        // 1600000
    const int NREG = (N + REGION_SIZE - 1) >> REGION_SHIFT;  // 196

    // --- d_out as raw scratch (fp32 final write overwrites all) ---
    u16* xb  = (u16*)d_out;                    // N*32 bf16
    u16* t0b = xb + (size_t)N * 32;            // N*32 bf16
    u16* t2b = (u16*)d_out + (size_t)N * 64;   // N*64 bf16

    // --- ws layout ---
    u16* t3b  = (u16*)d_ws;                    // N*64 bf16
    u32* stgk = (u32*)d_ws;                    // E u32 overlay (build only)
    u16* stgv = (u16*)((char*)d_ws + (size_t)E * 4);  // E u16 overlay
    int* row_ptr    = (int*)((char*)d_ws + (size_t)N * 64 * 2);  // N+1
    int* region_off = row_ptr + (N + 1);       // NREG+1
    int* partial    = region_off + (NREG + 1); // GBUILD*256
    int* bases      = partial + GBUILD * 256;  // GBUILD*256
    size_t wOff = (((size_t)((char*)(bases + GBUILD * 256) - (char*)d_ws)) + 15) & ~(size_t)15;
    u16* W1f = (u16*)((char*)d_ws + wOff);     // 2048 bf16
    u16* W2f = W1f + 2048;                     // 4096 bf16
    size_t cvOff = (((size_t)((char*)(W2f + 4096) - (char*)d_ws)) + 15) & ~(size_t)15;
    u32* cv = (u32*)((char*)d_ws + cvOff);     // E packed 4B edges

    int n4 = (N * 32) / 4;

    // ---- CSR build (2-pass radix, zero global atomics, no memset) ----
    region_count_kernel<<<GBUILD, 256, 0, stream>>>(edge_row, E, partial, x, xb, n4,
                                                    W1, W2, W1f, W2f);
    region_scanbase_kernel<<<NREG, 256, 0, stream>>>(partial, bases, region_off,
                                                     NREG, E, GBUILD);
    coarse_scatter_kernel<<<GBUILD, 256, 0, stream>>>(edge_row, edge_col, edge_val,
                                                      E, bases, stgk, stgv);
    region_sort_kernel<<<NREG, 256, 0, stream>>>(stgk, stgv, region_off,
                                                 row_ptr, cv, N, E);

    // ---- pipeline ----
    int g32 = (N * 4 + 255) / 256;   // D=32: 4 lanes/row (also 64 rows/block)
    int g64 = (N * 8 + 255) / 256;   // D=64: 8 lanes/row

    spmm_bf16_kernel<32, false><<<g32, 256, 0, stream>>>(xb, row_ptr, cv, t0b, nullptr, N);
    spmm_dense_kernel<<<g32, 256, 0, stream>>>(t0b, row_ptr, cv, W1f, b1, W2f, t2b, N);
    spmm_bf16_kernel<64, false><<<g64, 256, 0, stream>>>(t2b, row_ptr, cv, t3b, nullptr, N);
    spmm_bf16_kernel<64, true><<<g64, 256, 0, stream>>>(t3b, row_ptr, cv, out, b2, N);
}